// Round 17
// baseline (450.327 us; speedup 1.0000x reference)
//
#include <hip/hip_runtime.h>
#include <cstdint>

// Problem constants (static per reference)
#define T_TOK 16384     // B*S
#define HD    1024      // H
#define NE    8         // experts
#define CAP   2560      // ceil(1.25*T/E)
#define NCHUNK (T_TOK / 64)   // 256

typedef __attribute__((ext_vector_type(4))) float f32x4;
typedef __attribute__((ext_vector_type(8))) short bf16x8;   // 8 bf16 = 4 VGPRs

__device__ __forceinline__ unsigned short f2bf(float f) {
    union { float f; unsigned u; } x{f};
    unsigned r = x.u + 0x7FFF + ((x.u >> 16) & 1);   // RNE
    return (unsigned short)(r >> 16);
}

__device__ __forceinline__ float bf2f(unsigned short b) {
    union { unsigned u; float f; } x;
    x.u = ((unsigned)b) << 16;
    return x.f;
}

__device__ __forceinline__ void gload_lds16(const unsigned short* g, unsigned short* l) {
    __builtin_amdgcn_global_load_lds(
        (const __attribute__((address_space(1))) void*)g,
        (__attribute__((address_space(3))) void*)l, 16, 0, 0);
}

// ---------------------------------------------------------------------------
// bf16 MFMA GEMM: C[M,N] = op(A[M,K] @ Bt[N,K]^T [+ bias[N]])
// R12 structure (measured local optimum across R6..R16; all pipelining and
// schedule variants regressed): 256x128 tile, BK=64, 8 waves (4m x 2n),
// single-buffer 2-barrier loop; XCD bijective swizzle; XOR chunk-swizzle
// (0 bank conflicts); empty-tile early-exit for expert GEMMs.
// Epilogues:
//   RELU:               v = max(acc+bias, 0)
//   ROWSCALE:           v = rs[m]*(acc+bias)
//   SCATTER (+OUTBF16): tok=tab[m]; skip<0; in-place bf16 RMW:
//                       Cb[tok] = f2bf(bf2f(Cb[tok]) + v*rs[tok])   (R16)
//   SCATTER (f32):      Cf[tok] += v*rs[tok]
//   OUTBF16:            bf16 store else f32
// bias may be nullptr.
// ---------------------------------------------------------------------------
template<bool GATHER, bool RELU, bool ROWSCALE, bool SCATTER, bool OUTBF16>
__global__ __launch_bounds__(512)
void gemm_bf16_k(const unsigned short* __restrict__ A,
                 const unsigned short* __restrict__ Bt,
                 const float* __restrict__ bias,
                 void* __restrict__ Cv,
                 int M, int N, int K,
                 const int* __restrict__ idxTab,
                 const float* __restrict__ rs,
                 long aB, long bB, long biasB, long tabB, long cB)
{
    // ---- XCD-aware remap: XCD c gets contiguous logical chunk ----
    const int nx = gridDim.x, ny = gridDim.y;
    long nwg = (long)nx * ny * gridDim.z;
    long flat = blockIdx.x + (long)nx * (blockIdx.y + (long)ny * blockIdx.z);
    long cpx = nwg >> 3;                       // nwg % 8 == 0 by construction
    long swz = (flat & 7) * cpx + (flat >> 3);
    const int bx = (int)(swz % nx);
    const int by = (int)((swz / nx) % ny);
    const int bz = (int)(swz / ((long)nx * ny));

    A  += (long)bz * aB;
    Bt += (long)bz * bB;
    const float* bptr = bias ? bias + (long)bz * biasB : nullptr;
    const int* tab = idxTab ? idxTab + (long)bz * tabB : nullptr;
    float*          Cf = (float*)Cv + (long)bz * cB;
    unsigned short* Cb = (unsigned short*)Cv + (long)bz * cB;

    const int m0 = by * 256, n0 = bx * 128;

    // empty-tile early-exit (uniform across block; before any barrier)
    if ((GATHER || SCATTER) && tab[m0] < 0) return;

    __shared__ unsigned short As[256][64];   // 32 KB, row = m
    __shared__ unsigned short Bs[128][64];   // 16 KB, row = n  (48 KB total)

    const int tid  = threadIdx.x;
    const int wv   = tid >> 6;               // 0..7
    const int lane = tid & 63;

    // staging: issue = 8 rows x 128 B = 1024 B = 64 lanes x 16 B.
    const int srow = lane >> 3;
    const int schk = lane & 7;

    const unsigned short* aSrc[4];           // wave stages A rows wv*32..+31
    const unsigned short* bSrc[2];           // wave stages B rows wv*16..+15
    #pragma unroll
    for (int i = 0; i < 4; ++i) {
        int lrow = wv * 32 + i * 8 + srow;          // 0..255
        int scol = ((schk ^ (lrow & 7)) * 8);       // swizzled col (elems)
        long sr;
        if (GATHER) { int tr = tab[m0 + lrow]; sr = tr < 0 ? 0 : tr; }
        else        sr = m0 + lrow;
        aSrc[i] = A + sr * (long)K + scol;
    }
    #pragma unroll
    for (int i = 0; i < 2; ++i) {
        int lrow = wv * 16 + i * 8 + srow;          // 0..127
        int scol = ((schk ^ (lrow & 7)) * 8);
        bSrc[i] = Bt + (long)(n0 + lrow) * K + scol;
    }

    f32x4 acc[4][4] = {};
    const int wm = wv >> 1, wn = wv & 1;     // 4 x 2 wave grid
    const int fr = lane & 15, kg = lane >> 4;

    for (int k0 = 0; k0 < K; k0 += 64) {
        __syncthreads();                     // prev tile fully consumed
        #pragma unroll
        for (int i = 0; i < 4; ++i)
            gload_lds16(aSrc[i] + k0, &As[wv * 32 + i * 8][0]);
        #pragma unroll
        for (int i = 0; i < 2; ++i)
            gload_lds16(bSrc[i] + k0, &Bs[wv * 16 + i * 8][0]);
        __syncthreads();                     // vmcnt(0) drained here

        #pragma unroll
        for (int kk = 0; kk < 2; ++kk) {     // two K=32 halves of BK=64
            bf16x8 af[4], bfr[4];
            #pragma unroll
            for (int i2 = 0; i2 < 4; ++i2) {
                int R = wm * 64 + i2 * 16 + fr;
                af[i2] = *(const bf16x8*)&As[R][((kk * 4 + kg) ^ (R & 7)) * 8];
            }
            #pragma unroll
            for (int j2 = 0; j2 < 4; ++j2) {
                int R = wn * 64 + j2 * 16 + fr;
                bfr[j2] = *(const bf16x8*)&Bs[R][((kk * 4 + kg) ^ (R & 7)) * 8];
            }
            #pragma unroll
            for (int i2 = 0; i2 < 4; ++i2)
                #pragma unroll
                for (int j2 = 0; j2 < 4; ++j2)
                    acc[i2][j2] = __builtin_amdgcn_mfma_f32_16x16x32_bf16(
                        af[i2], bfr[j2], acc[i2][j2], 0, 0, 0);
        }
    }

    // epilogue: C/D layout col = lane&15, row = (lane>>4)*4 + r
    const int colL = lane & 15, rgrp = (lane >> 4) * 4;
    #pragma unroll
    for (int i2 = 0; i2 < 4; ++i2) {
        #pragma unroll
        for (int r = 0; r < 4; ++r) {
            int gm = m0 + wm * 64 + i2 * 16 + rgrp + r;
            int token = gm; float sc = 1.0f;
            if (SCATTER) {
                token = tab[gm];
                if (token < 0) continue;
                sc = rs[token];
            } else if (ROWSCALE) {
                sc = rs[gm];
            }
            #pragma unroll
            for (int j2 = 0; j2 < 4; ++j2) {
                int gn = n0 + wn * 64 + j2 * 16 + colL;
                float v = acc[i2][j2][r] + (bptr ? bptr[gn] : 0.0f);
                if (RELU) v = fmaxf(v, 0.0f);
                if (SCATTER) {
                    long idx = (long)token * N + gn;
                    if (OUTBF16) {
                        // in-place bf16 RMW (unique writer; j rewrites the
                        // buffer before k on every call -> replay-safe)
                        Cb[idx] = f2bf(bf2f(Cb[idx]) + v * sc);
                    } else {
                        Cf[idx] += v * sc;
                    }
                } else {
                    if (ROWSCALE) v *= sc;
                    if (OUTBF16) Cb[(long)gm * N + gn] = f2bf(v);
                    else         Cf[(long)gm * N + gn] = v;
                }
            }
        }
    }
}

// ---------------------------------------------------------------------------
// f32 -> bf16 cast (vectorized, grid-stride)
// ---------------------------------------------------------------------------
__global__ __launch_bounds__(256)
void cast_bf16_k(const float* __restrict__ in, unsigned short* __restrict__ out,
                 long n4)
{
    long i = (long)blockIdx.x * 256 + threadIdx.x;
    long stride = (long)gridDim.x * 256;
    for (; i < n4; i += stride) {
        float4 v = ((const float4*)in)[i];
        ushort4 o;
        o.x = f2bf(v.x); o.y = f2bf(v.y); o.z = f2bf(v.z); o.w = f2bf(v.w);
        ((ushort4*)out)[i] = o;
    }
}

// ---------------------------------------------------------------------------
// Transpose + cast: W[K][N] f32 -> Wt[N][K] bf16, 64x64 LDS tiles. z batched.
// ---------------------------------------------------------------------------
__global__ __launch_bounds__(256)
void transpose_cast_k(const float* __restrict__ W, unsigned short* __restrict__ Wt,
                      int K, int N, long wB, long wtB)
{
    const int z = blockIdx.z;
    W  += (long)z * wB;
    Wt += (long)z * wtB;
    __shared__ float tile[64][65];
    const int k0 = blockIdx.x * 64, n0 = blockIdx.y * 64;
    const int c = threadIdx.x & 63, r4 = threadIdx.x >> 6;
    #pragma unroll 4
    for (int it = 0; it < 16; ++it) {
        int row = it * 4 + r4;
        tile[row][c] = W[(long)(k0 + row) * N + n0 + c];
    }
    __syncthreads();
    #pragma unroll 4
    for (int it = 0; it < 16; ++it) {
        int nrow = it * 4 + r4;
        Wt[(long)(n0 + nrow) * K + k0 + c] = f2bf(tile[c][nrow]);
    }
}

// ---------------------------------------------------------------------------
// Fused-bias helpers: out[z][n] = sum_k v[z*vB+k] * W[z*wB + k*HD + n] (+badd)
// init writes badd (or 0); acc atomically adds K-chunk partials.
// (refcheck-verified in R13/R14 passing runs)
// ---------------------------------------------------------------------------
__global__ void vecmat_init_k(const float* __restrict__ badd, long bB,
                              float* __restrict__ out, long oB)
{
    const int z = blockIdx.y;
    const int n = blockIdx.x * 256 + threadIdx.x;
    out[z * oB + n] = badd ? badd[z * bB + n] : 0.0f;
}

__global__ void vecmat_acc_k(const float* __restrict__ v, long vB,
                             const float* __restrict__ W, long wB,
                             float* __restrict__ out, long oB)
{
    const int z = blockIdx.z;
    const int n = blockIdx.x * 256 + threadIdx.x;
    const int kc = blockIdx.y;             // K chunk of 128
    const float* vp = v + z * vB;
    const float* Wp = W + z * wB;
    float acc = 0.f;
    #pragma unroll 8
    for (int k = kc * 128; k < kc * 128 + 128; ++k)
        acc = fmaf(vp[k], Wp[(long)k * HD + n], acc);
    atomicAdd(out + z * oB + n, acc);
}

// ---------------------------------------------------------------------------
// Wsmall: Wg'[H][8] = W_in @ W_gate, Wc'[H][2] = W_in @ W_coef  (f32)
// ---------------------------------------------------------------------------
__global__ __launch_bounds__(256)
void wsmall_k(const float* __restrict__ W_in, const float* __restrict__ W_gate,
              const float* __restrict__ W_coef,
              float* __restrict__ wgp, float* __restrict__ wcp)
{
    const int r = blockIdx.x * 4 + (threadIdx.x >> 6);
    const int lane = threadIdx.x & 63;
    float s[10] = {};
    for (int k = lane; k < HD; k += 64) {
        float a = W_in[(long)r * HD + k];
        const float4* g = (const float4*)(W_gate + (long)k * 8);
        float4 g0 = g[0], g1 = g[1];
        s[0] += a * g0.x; s[1] += a * g0.y; s[2] += a * g0.z; s[3] += a * g0.w;
        s[4] += a * g1.x; s[5] += a * g1.y; s[6] += a * g1.z; s[7] += a * g1.w;
        float2 cv = *(const float2*)(W_coef + (long)k * 2);
        s[8] += a * cv.x; s[9] += a * cv.y;
    }
    #pragma unroll
    for (int off = 32; off > 0; off >>= 1)
        #pragma unroll
        for (int e = 0; e < 10; ++e) s[e] += __shfl_xor(s[e], off);
    if (lane == 0) {
        #pragma unroll
        for (int e = 0; e < 8; ++e) wgp[(long)r * 8 + e] = s[e];
        wcp[(long)r * 2 + 0] = s[8];
        wcp[(long)r * 2 + 1] = s[9];
    }
}

// bg[8] = b_in @ W_gate ; bc[2] = b_in @ W_coef + b_coef
__global__ void gbias_k(const float* __restrict__ b_in, const float* __restrict__ W_gate,
                        const float* __restrict__ W_coef, const float* __restrict__ b_coef,
                        float* __restrict__ bg, float* __restrict__ bc)
{
    const int lane = threadIdx.x;  // 64
    float s[10] = {};
    for (int k = lane; k < HD; k += 64) {
        float a = b_in[k];
        const float4* g = (const float4*)(W_gate + (long)k * 8);
        float4 g0 = g[0], g1 = g[1];
        s[0] += a * g0.x; s[1] += a * g0.y; s[2] += a * g0.z; s[3] += a * g0.w;
        s[4] += a * g1.x; s[5] += a * g1.y; s[6] += a * g1.z; s[7] += a * g1.w;
        float2 cv = *(const float2*)(W_coef + (long)k * 2);
        s[8] += a * cv.x; s[9] += a * cv.y;
    }
    #pragma unroll
    for (int off = 32; off > 0; off >>= 1)
        #pragma unroll
        for (int e = 0; e < 10; ++e) s[e] += __shfl_xor(s[e], off);
    if (lane == 0) {
        #pragma unroll
        for (int e = 0; e < 8; ++e) bg[e] = s[e];
        bc[0] = s[8] + b_coef[0];
        bc[1] = s[9] + b_coef[1];
    }
}

// ---------------------------------------------------------------------------
// Gating from x with fused weights (one wave per token) + fused x->bf16 cast.
// ---------------------------------------------------------------------------
__global__ __launch_bounds__(256)
void gating_k(const float* __restrict__ x,
              const float* __restrict__ Wg,   // [H,8] fused
              const float* __restrict__ Wc,   // [H,2] fused
              const float* __restrict__ bg,   // [8]
              const float* __restrict__ bc,   // [2]
              unsigned short* __restrict__ xb,
              int* __restrict__ eidx,
              float* __restrict__ gval,
              float* __restrict__ coef0,
              float* __restrict__ coef1)
{
    const int tok = (blockIdx.x * 256 + threadIdx.x) >> 6;
    const int lane = threadIdx.x & 63;
    const float* row = x + (long)tok * HD;
    unsigned short* orow = xb + (long)tok * HD;

    float acc[8] = {};
    float c0 = 0.f, c1 = 0.f;
    for (int i = 0; i < HD / 64; ++i) {
        int k = i * 64 + lane;
        float tv = row[k];
        orow[k] = f2bf(tv);                      // fused x -> bf16 (coalesced)
        const float4* wg = (const float4*)(Wg + (long)k * 8);
        float4 w0 = wg[0], w1 = wg[1];
        acc[0] = fmaf(tv, w0.x, acc[0]); acc[1] = fmaf(tv, w0.y, acc[1]);
        acc[2] = fmaf(tv, w0.z, acc[2]); acc[3] = fmaf(tv, w0.w, acc[3]);
        acc[4] = fmaf(tv, w1.x, acc[4]); acc[5] = fmaf(tv, w1.y, acc[5]);
        acc[6] = fmaf(tv, w1.z, acc[6]); acc[7] = fmaf(tv, w1.w, acc[7]);
        float2 wcv = *(const float2*)(Wc + (long)k * 2);
        c0 = fmaf(tv, wcv.x, c0);
        c1 = fmaf(tv, wcv.y, c1);
    }
    #pragma unroll
    for (int off = 32; off > 0; off >>= 1) {
        #pragma unroll
        for (int e = 0; e < 8; ++e) acc[e] += __shfl_xor(acc[e], off);
        c0 += __shfl_xor(c0, off);
        c1 += __shfl_xor(c1, off);
    }
    if (lane == 0) {
        #pragma unroll
        for (int e = 0; e < 8; ++e) acc[e] += bg[e];
        float m = acc[0]; int best = 0;
        #pragma unroll
        for (int e = 1; e < 8; ++e) if (acc[e] > m) { m = acc[e]; best = e; }
        float s = 0.f;
        #pragma unroll
        for (int e = 0; e < 8; ++e) s += expf(acc[e] - m);
        eidx[tok] = best;
        gval[tok] = 1.0f / s;
        float l0 = c0 + bc[0], l1 = c1 + bc[1];
        float mm = fmaxf(l0, l1);
        float e0 = expf(l0 - mm), e1 = expf(l1 - mm);
        float inv = 1.0f / (e0 + e1);
        coef0[tok] = e0 * inv;
        coef1[tok] = e1 * inv;
    }
}

// ---------------------------------------------------------------------------
// Parallel capacity scan, 3 phases (integer-exact, verified round 5).
// ---------------------------------------------------------------------------
__global__ void scan_hist_k(const int* __restrict__ eidx,
                            int* __restrict__ counts,
                            int* __restrict__ idxTab)
{
    const int b = blockIdx.x;          // chunk id, 0..255
    const int lane = threadIdx.x;      // 64
    for (int j = b * 64 + lane; j < NE * CAP; j += NCHUNK * 64)
        idxTab[j] = -1;
    int e = eidx[b * 64 + lane];
    #pragma unroll
    for (int ex = 0; ex < NE; ++ex) {
        unsigned long long msk = __ballot(e == ex);
        if (lane == ex) counts[b * NE + ex] = (int)__popcll(msk);
    }
}

__global__ void scan_offsets_k(const int* __restrict__ counts,
                               int* __restrict__ offsets)
{
    const int e = threadIdx.x;         // 64 threads, 8 active
    if (e < NE) {
        int run = 0;
        for (int b = 0; b < NCHUNK; ++b) {
            offsets[b * NE + e] = run;
            run += counts[b * NE + e];
        }
    }
}

__global__ void scan_fill_k(const int* __restrict__ eidx,
                            const float* __restrict__ gval,
                            const float* __restrict__ coef0,
                            const int* __restrict__ offsets,
                            int* __restrict__ idxTab,
                            float* __restrict__ smoe)
{
    const int b = blockIdx.x;
    const int lane = threadIdx.x;
    const int tok = b * 64 + lane;
    int e = eidx[tok];
    unsigned long long below = (lane == 0) ? 0ull : ((~0ull) >> (64 - lane));
    int myrank = 0;
    #pragma unroll
    for (int ex = 0; ex < NE; ++ex) {
        unsigned long long msk = __ballot(e == ex);
        if (e == ex) myrank = (int)__popcll(msk & below) + offsets[b * NE + ex];
    }
    if (myrank < CAP) {
        idxTab[e * CAP + myrank] = tok;
        smoe[tok] = gval[tok] * coef0[tok];
    } else {
        smoe[tok] = 0.0f;
    }
}

// ---------------------------------------------------------------------------
// Workspace plan (lifetime-aliased; ~142 MB, under proven 144.4):
//   [0,40Mi):   pre-fusion W1T(16,z8)+Wr1T(2)+Winp(2) — dead after fusion;
//               h(40) overlays from FC1 on
//   [40,58Mi):  WF1T(16)+WFr1T(2)  (fused input weights; C-batch z=9)
//   [58,78Mi):  W2T(16)+Wr2T(2)+WoutT(2)  (tail weights)
//   [78,110Mi): res1 (32, written res1-step, read j)
//   [110,142Mi):mixb (32, written j, RMW k, read m)
//   [142Mi..):  small (biases, routing arrays)
//   xb: d_out[0,32Mi) bf16 (gating..res1);  out: d_out f32 (written m)
// ---------------------------------------------------------------------------
extern "C" void kernel_launch(void* const* d_in, const int* in_sizes, int n_in,
                              void* d_out, int out_size, void* d_ws, size_t ws_size,
                              hipStream_t stream)
{
    const float* x      = (const float*)d_in[0];
    const float* W_in   = (const float*)d_in[1];
    const float* b_in   = (const float*)d_in[2];
    const float* W_gate = (const float*)d_in[3];
    const float* W1     = (const float*)d_in[4];
    const float* b1     = (const float*)d_in[5];
    const float* W2     = (const float*)d_in[6];
    const float* b2     = (const float*)d_in[7];
    const float* Wr1    = (const float*)d_in[8];
    const float* br1    = (const float*)d_in[9];
    const float* Wr2    = (const float*)d_in[10];
    const float* br2    = (const float*)d_in[11];
    const float* W_coef = (const float*)d_in[12];
    const float* b_coef = (const float*)d_in[13];
    const float* W_out  = (const float*)d_in[14];
    const float* b_out  = (const float*)d_in[15];
    float* out = (float*)d_out;

    const size_t MiB = 1024 * 1024;
    char* ws = (char*)d_ws;
    // pre-fusion (dead after fusion GEMM); h overlays [0,40Mi)
    unsigned short* W1T   = (unsigned short*)(ws + 0);         // 16 MiB (z=8)
    unsigned short* Wr1T  = (unsigned short*)(ws + 16 * MiB);  // 2 MiB (A-batch z=8)
    unsigned short* Winp  = (unsigned short*)(ws + 18 * MiB);  // 2 MiB plain cast
    unsigned short* h     = (unsigned short*)(ws + 0);         // 40 MiB overlay
    // fused input-side weights
    unsigned short* WF1T  = (unsigned short*)(ws + 40 * MiB);  // 16 MiB
    unsigned short* WFr1T = (unsigned short*)(ws + 56 * MiB);  // 2 MiB (C-batch z=8)
    // tail weights
    unsigned short* W2T   = (unsigned short*)(ws + 58 * MiB);  // 16 MiB
    unsigned short* Wr2T  = (unsigned short*)(ws + 74 * MiB);  // 2 MiB
    unsigned short* WoutT = (unsigned short*)(ws + 76 * MiB);  // 2 MiB
    unsigned short* res1  = (unsigned short*)(ws + 78 * MiB);  // 32 MiB
    unsigned short* mixb  = (unsigned short*)(ws + 110 * MiB); // 32 MiB
    char* sm = ws + 142 * MiB;
    float* wgp  = (float*)(sm);            sm += HD * 8 * 4;
    float* wcp  = (float*)(sm);            sm += HD * 2 * 4;
    float* bg   = (float*)(sm);            sm += 64;
    float* bc   = (float*)(sm);            sm += 64;
    float* bf1  = (float*)(sm);            sm += NE * HD * 4;   // b_in@W1[e]+b1[e]
    float* bfr1 = (float*)(sm);            sm += HD * 4;        // b_in@Wr1+br1
    int*   eidx = (int*)(sm);              sm += T_TOK * 4;
    float* gval = (float*)(sm);            sm += T_TOK * 4;
    float* cf0  = (float*)(sm);            sm += T_TOK * 4;
    float* cf1  = (float*)(sm);            sm += T_TOK * 4;
    float* smoe = (float*)(sm);            sm += T_TOK * 4;
    int* idxTab = (int*)(sm);              sm += NE * CAP * 4;
    int* counts = (int*)(sm);              sm += NCHUNK * NE * 4;
    int* offs   = (int*)(sm);              sm += NCHUNK * NE * 4;
    unsigned short* xb = (unsigned short*)d_out;   // bf16, dead after res1
    (void)ws_size; (void)in_sizes; (void)n_in; (void)out_size;

    const long HD2 = (long)HD * HD;
    dim3 blk(256);
    dim3 blkG(512);
    dim3 gT(16, 16, 1);
    dim3 gT8(16, 16, 8);
    dim3 gBig(HD / 128, T_TOK / 256, 1);   // 8 x 64 = 512 blocks (%8==0)
    dim3 gExp(HD / 128, CAP / 256, NE);    // 8 x 10 x 8 = 640 blocks (%8==0)
    dim3 gFuse(HD / 128, HD / 256, 9);     // 8 x 4 x 9 = 288 blocks (%8==0)

    // 1. weight transposes (bf16 [N][K])
    transpose_cast_k<<<gT8, blk, 0, stream>>>(W1, W1T, HD, HD, HD2, HD2);
    transpose_cast_k<<<gT,  blk, 0, stream>>>(Wr1,   Wr1T,  HD, HD, 0, 0);
    transpose_cast_k<<<gT8, blk, 0, stream>>>(W2, W2T, HD, HD, HD2, HD2);
    transpose_cast_k<<<gT,  blk, 0, stream>>>(Wr2,   Wr2T,  HD, HD, 0, 0);
    transpose_cast_k<<<gT,  blk, 0, stream>>>(W_out, WoutT, HD, HD, 0, 0);
    // 2. plain cast — fusion Bt operand
    cast_bf16_k<<<512, blk, 0, stream>>>(W_in, Winp, HD2 / 4);
    // 3. fused gating weights + biases (f32 routing path)
    wsmall_k<<<HD / 4, blk, 0, stream>>>(W_in, W_gate, W_coef, wgp, wcp);
    gbias_k<<<1, 64, 0, stream>>>(b_in, W_gate, W_coef, b_coef, bg, bc);
    // 4. fused biases bf1, bfr1 (R13/R14-verified)
    vecmat_init_k<<<dim3(HD/256, NE), blk, 0, stream>>>(b1, HD, bf1, HD);
    vecmat_acc_k <<<dim3(HD/256, 8, NE), blk, 0, stream>>>(b_in, 0, W1, HD2, bf1, HD);
    vecmat_init_k<<<dim3(HD/256, 1), blk, 0, stream>>>(br1, 0, bfr1, 0);
    vecmat_acc_k <<<dim3(HD/256, 8, 1), blk, 0, stream>>>(b_in, 0, Wr1, 0, bfr1, 0);
    // 5. gating from x (f32 routing) + fused x->bf16 cast into d_out
    gating_k<<<T_TOK / 4, blk, 0, stream>>>(x, wgp, wcp, bg, bc, xb,
                                            eidx, gval, cf0, cf1);
    // 6. parallel capacity scan
    scan_hist_k<<<NCHUNK, 64, 0, stream>>>(eidx, counts, idxTab);
    scan_offsets_k<<<1, 64, 0, stream>>>(counts, offs);
    scan_fill_k<<<NCHUNK, 64, 0, stream>>>(eidx, gval, cf0, offs, idxTab, smoe);
    // 7. input-side weight fusion: [WF1T(8), WFr1T] = [W1T(8), Wr1T] x Winp
    //    (z=9 batched; orientation refcheck-verified in R13/R14)
    gemm_bf16_k<false, false, false, false, true><<<gFuse, blkG, 0, stream>>>(
        W1T, Winp, nullptr, WF1T, HD, HD, HD, nullptr, nullptr,
        HD2, 0, 0, 0, HD2);
    // 8. FC1: h[e] = relu(gather(xb) @ WF1[e] + bf1[e])  bf16, empty-tile exit
    gemm_bf16_k<true, true, false, false, true><<<gExp, blkG, 0, stream>>>(
        xb, WF1T, bf1, h, CAP, HD, HD, idxTab, nullptr,
        0, HD2, HD, CAP, (long)CAP * HD);
    // 9. res1 = relu(xb @ WFr1 + bfr1)   bf16
    gemm_bf16_k<false, true, false, false, true><<<gBig, blkG, 0, stream>>>(
        xb, WFr1T, bfr1, res1, T_TOK, HD, HD, nullptr, nullptr,
        0, 0, 0, 0, 0);
    // 10. j: mixb = bf16((res1 @ Wr2 + br2) * cf1[row])  bf16 (halved WRITE)
    gemm_bf16_k<false, false, true, false, true><<<gBig, blkG, 0, stream>>>(
        res1, Wr2T, br2, mixb, T_TOK, HD, HD, nullptr, cf1,
        0, 0, 0, 0, 0);
    // 11. k: mixb[tok] = bf16(f32(mixb[tok]) + (h[e]@W2[e]+b2[e])*smoe[tok])
    //     in-place bf16 RMW, empty-tile exit; dropped rows already final
    gemm_bf16_k<false, false, false, true, true><<<gExp, blkG, 0, stream>>>(
        h, W2T, b2, mixb, CAP, HD, HD, idxTab, smoe,
        (long)CAP * HD, HD2, HD, CAP, 0);
    // 12. m: out = mixb @ W_out + b_out   f32 -> d_out
    gemm_bf16_k<false, false, false, false, false><<<gBig, blkG, 0, stream>>>(
        mixb, WoutT, b_out, out, T_TOK, HD, HD, nullptr, nullptr,
        0, 0, 0, 0, 0);
}

// Round 18
// 427.427 us; speedup vs baseline: 1.0536x; 1.0536x over previous
//
#include <hip/hip_runtime.h>
#include <cstdint>

// Problem constants (static per reference)
#define T_TOK 16384     // B*S
#define HD    1024      // H
#define NE    8         // experts
#define CAP   2560      // ceil(1.25*T/E)
#define NCHUNK (T_TOK / 64)   // 256

typedef __attribute__((ext_vector_type(4))) float f32x4;
typedef __attribute__((ext_vector_type(8))) short bf16x8;   // 8 bf16 = 4 VGPRs

__device__ __forceinline__ unsigned short f2bf(float f) {
    union { float f; unsigned u; } x{f};
    unsigned r = x.u + 0x7FFF + ((x.u >> 16) & 1);   // RNE
    return (unsigned short)(r >> 16);
}

__device__ __forceinline__ float bf2f(unsigned short b) {
    union { unsigned u; float f; } x;
    x.u = ((unsigned)b) << 16;
    return x.f;
}

__device__ __forceinline__ void gload_lds16(const unsigned short* g, unsigned short* l) {
    __builtin_amdgcn_global_load_lds(
        (const __attribute__((address_space(1))) void*)g,
        (__attribute__((address_space(3))) void*)l, 16, 0, 0);
}

// ---------------------------------------------------------------------------
// bf16 MFMA GEMM: C[M,N] = op(A[M,K] @ Bt[N,K]^T [+ bias[N]])
// R12 structure (measured local optimum across R6..R17; all pipelining and
// schedule variants regressed): 256x128 tile, BK=64, 8 waves (4m x 2n),
// single-buffer 2-barrier loop; XCD bijective swizzle; XOR chunk-swizzle
// (0 bank conflicts); empty-tile early-exit for expert GEMMs.
// Epilogues:
//   RELU:               v = max(acc+bias, 0)
//   ROWSCALE:           v = rs[m]*(acc+bias)
//   SCATTER (+OUTBF16): tok=tab[m]; skip<0; in-place bf16 RMW:
//                       Cb[tok] = f2bf(bf2f(Cb[tok]) + v*rs[tok])   (R16)
//   SCATTER (f32):      Cf[tok] += v*rs[tok]
//   OUTBF16:            bf16 store else f32
// bias may be nullptr.
// ---------------------------------------------------------------------------
template<bool GATHER, bool RELU, bool ROWSCALE, bool SCATTER, bool OUTBF16>
__global__ __launch_bounds__(512)
void gemm_bf16_k(const unsigned short* __restrict__ A,
                 const unsigned short* __restrict__ Bt,
                 const float* __restrict__ bias,
                 void* __restrict__ Cv,
                 int M, int N, int K,
                 const int* __restrict__ idxTab,
                 const float* __restrict__ rs,
                 long aB, long bB, long biasB, long tabB, long cB)
{
    // ---- XCD-aware remap: XCD c gets contiguous logical chunk ----
    const int nx = gridDim.x, ny = gridDim.y;
    long nwg = (long)nx * ny * gridDim.z;
    long flat = blockIdx.x + (long)nx * (blockIdx.y + (long)ny * blockIdx.z);
    long cpx = nwg >> 3;                       // nwg % 8 == 0 by construction
    long swz = (flat & 7) * cpx + (flat >> 3);
    const int bx = (int)(swz % nx);
    const int by = (int)((swz / nx) % ny);
    const int bz = (int)(swz / ((long)nx * ny));

    A  += (long)bz * aB;
    Bt += (long)bz * bB;
    const float* bptr = bias ? bias + (long)bz * biasB : nullptr;
    const int* tab = idxTab ? idxTab + (long)bz * tabB : nullptr;
    float*          Cf = (float*)Cv + (long)bz * cB;
    unsigned short* Cb = (unsigned short*)Cv + (long)bz * cB;

    const int m0 = by * 256, n0 = bx * 128;

    // empty-tile early-exit (uniform across block; before any barrier)
    if ((GATHER || SCATTER) && tab[m0] < 0) return;

    __shared__ unsigned short As[256][64];   // 32 KB, row = m
    __shared__ unsigned short Bs[128][64];   // 16 KB, row = n  (48 KB total)

    const int tid  = threadIdx.x;
    const int wv   = tid >> 6;               // 0..7
    const int lane = tid & 63;

    // staging: issue = 8 rows x 128 B = 1024 B = 64 lanes x 16 B.
    const int srow = lane >> 3;
    const int schk = lane & 7;

    const unsigned short* aSrc[4];           // wave stages A rows wv*32..+31
    const unsigned short* bSrc[2];           // wave stages B rows wv*16..+15
    #pragma unroll
    for (int i = 0; i < 4; ++i) {
        int lrow = wv * 32 + i * 8 + srow;          // 0..255
        int scol = ((schk ^ (lrow & 7)) * 8);       // swizzled col (elems)
        long sr;
        if (GATHER) { int tr = tab[m0 + lrow]; sr = tr < 0 ? 0 : tr; }
        else        sr = m0 + lrow;
        aSrc[i] = A + sr * (long)K + scol;
    }
    #pragma unroll
    for (int i = 0; i < 2; ++i) {
        int lrow = wv * 16 + i * 8 + srow;          // 0..127
        int scol = ((schk ^ (lrow & 7)) * 8);
        bSrc[i] = Bt + (long)(n0 + lrow) * K + scol;
    }

    f32x4 acc[4][4] = {};
    const int wm = wv >> 1, wn = wv & 1;     // 4 x 2 wave grid
    const int fr = lane & 15, kg = lane >> 4;

    for (int k0 = 0; k0 < K; k0 += 64) {
        __syncthreads();                     // prev tile fully consumed
        #pragma unroll
        for (int i = 0; i < 4; ++i)
            gload_lds16(aSrc[i] + k0, &As[wv * 32 + i * 8][0]);
        #pragma unroll
        for (int i = 0; i < 2; ++i)
            gload_lds16(bSrc[i] + k0, &Bs[wv * 16 + i * 8][0]);
        __syncthreads();                     // vmcnt(0) drained here

        #pragma unroll
        for (int kk = 0; kk < 2; ++kk) {     // two K=32 halves of BK=64
            bf16x8 af[4], bfr[4];
            #pragma unroll
            for (int i2 = 0; i2 < 4; ++i2) {
                int R = wm * 64 + i2 * 16 + fr;
                af[i2] = *(const bf16x8*)&As[R][((kk * 4 + kg) ^ (R & 7)) * 8];
            }
            #pragma unroll
            for (int j2 = 0; j2 < 4; ++j2) {
                int R = wn * 64 + j2 * 16 + fr;
                bfr[j2] = *(const bf16x8*)&Bs[R][((kk * 4 + kg) ^ (R & 7)) * 8];
            }
            #pragma unroll
            for (int i2 = 0; i2 < 4; ++i2)
                #pragma unroll
                for (int j2 = 0; j2 < 4; ++j2)
                    acc[i2][j2] = __builtin_amdgcn_mfma_f32_16x16x32_bf16(
                        af[i2], bfr[j2], acc[i2][j2], 0, 0, 0);
        }
    }

    // epilogue: C/D layout col = lane&15, row = (lane>>4)*4 + r
    const int colL = lane & 15, rgrp = (lane >> 4) * 4;
    #pragma unroll
    for (int i2 = 0; i2 < 4; ++i2) {
        #pragma unroll
        for (int r = 0; r < 4; ++r) {
            int gm = m0 + wm * 64 + i2 * 16 + rgrp + r;
            int token = gm; float sc = 1.0f;
            if (SCATTER) {
                token = tab[gm];
                if (token < 0) continue;
                sc = rs[token];
            } else if (ROWSCALE) {
                sc = rs[gm];
            }
            #pragma unroll
            for (int j2 = 0; j2 < 4; ++j2) {
                int gn = n0 + wn * 64 + j2 * 16 + colL;
                float v = acc[i2][j2][r] + (bptr ? bptr[gn] : 0.0f);
                if (RELU) v = fmaxf(v, 0.0f);
                if (SCATTER) {
                    long idx = (long)token * N + gn;
                    if (OUTBF16) {
                        // in-place bf16 RMW (unique writer; j rewrites the
                        // buffer before k on every call -> replay-safe)
                        Cb[idx] = f2bf(bf2f(Cb[idx]) + v * sc);
                    } else {
                        Cf[idx] += v * sc;
                    }
                } else {
                    if (ROWSCALE) v *= sc;
                    if (OUTBF16) Cb[(long)gm * N + gn] = f2bf(v);
                    else         Cf[(long)gm * N + gn] = v;
                }
            }
        }
    }
}

// ---------------------------------------------------------------------------
// Combined weight prep (R18): one launch replaces 5 transpose_cast + 1 cast.
// z 0..7:  W1[z]  -> W1T[z]   (transpose+cast, [N][K])
// z 8..15: W2[z-8]-> W2T[z-8] (transpose+cast)
// z 16:    Wr1 -> Wr1T;  z 17: Wr2 -> Wr2T;  z 18: W_out -> WoutT
// z 19:    W_in -> Winp (plain cast, row-major kept)
// ---------------------------------------------------------------------------
__global__ __launch_bounds__(256)
void prep_weights_k(const float* __restrict__ W1, const float* __restrict__ W2,
                    const float* __restrict__ Wr1, const float* __restrict__ Wr2,
                    const float* __restrict__ W_out, const float* __restrict__ W_in,
                    unsigned short* __restrict__ W1T, unsigned short* __restrict__ W2T,
                    unsigned short* __restrict__ Wr1T, unsigned short* __restrict__ Wr2T,
                    unsigned short* __restrict__ WoutT, unsigned short* __restrict__ Winp)
{
    const int z = blockIdx.z;
    const float* W;
    unsigned short* Wt;
    bool tr = true;
    const long HD2 = (long)HD * HD;
    if (z < 8)       { W = W1 + (long)z * HD2;       Wt = W1T + (long)z * HD2; }
    else if (z < 16) { W = W2 + (long)(z - 8) * HD2; Wt = W2T + (long)(z - 8) * HD2; }
    else if (z == 16){ W = Wr1;   Wt = Wr1T; }
    else if (z == 17){ W = Wr2;   Wt = Wr2T; }
    else if (z == 18){ W = W_out; Wt = WoutT; }
    else             { W = W_in;  Wt = Winp; tr = false; }

    __shared__ float tile[64][65];
    const int k0 = blockIdx.x * 64, n0 = blockIdx.y * 64;
    const int c = threadIdx.x & 63, r4 = threadIdx.x >> 6;
    #pragma unroll 4
    for (int it = 0; it < 16; ++it) {
        int row = it * 4 + r4;
        tile[row][c] = W[(long)(k0 + row) * HD + n0 + c];
    }
    __syncthreads();
    if (tr) {
        #pragma unroll 4
        for (int it = 0; it < 16; ++it) {
            int nrow = it * 4 + r4;
            Wt[(long)(n0 + nrow) * HD + k0 + c] = f2bf(tile[c][nrow]);
        }
    } else {
        #pragma unroll 4
        for (int it = 0; it < 16; ++it) {
            int row = it * 4 + r4;
            Wt[(long)(k0 + row) * HD + n0 + c] = f2bf(tile[row][c]);
        }
    }
}

// ---------------------------------------------------------------------------
// Fused-bias helpers: out[z][n] = sum_k v[z*vB+k] * W[z*wB + k*HD + n] (+badd)
// init writes badd (or 0); acc atomically adds K-chunk partials.
// (refcheck-verified in R13/R14/R17 passing runs)
// ---------------------------------------------------------------------------
__global__ void vecmat_init_k(const float* __restrict__ badd, long bB,
                              float* __restrict__ out, long oB)
{
    const int z = blockIdx.y;
    const int n = blockIdx.x * 256 + threadIdx.x;
    out[z * oB + n] = badd ? badd[z * bB + n] : 0.0f;
}

__global__ void vecmat_acc_k(const float* __restrict__ v, long vB,
                             const float* __restrict__ W, long wB,
                             float* __restrict__ out, long oB)
{
    const int z = blockIdx.z;
    const int n = blockIdx.x * 256 + threadIdx.x;
    const int kc = blockIdx.y;             // K chunk of 128
    const float* vp = v + z * vB;
    const float* Wp = W + z * wB;
    float acc = 0.f;
    #pragma unroll 8
    for (int k = kc * 128; k < kc * 128 + 128; ++k)
        acc = fmaf(vp[k], Wp[(long)k * HD + n], acc);
    atomicAdd(out + z * oB + n, acc);
}

// ---------------------------------------------------------------------------
// Fused gating weights (R18: gbias merged in as the extra block 256):
//   blocks 0..255: Wg'[r][8] = W_in[r,:]@W_gate, Wc'[r][2] = W_in[r,:]@W_coef
//   block 256 (first wave): bg = b_in@W_gate, bc = b_in@W_coef + b_coef
// ---------------------------------------------------------------------------
__global__ __launch_bounds__(256)
void wsmall_k(const float* __restrict__ W_in, const float* __restrict__ b_in,
              const float* __restrict__ W_gate, const float* __restrict__ W_coef,
              const float* __restrict__ b_coef,
              float* __restrict__ wgp, float* __restrict__ wcp,
              float* __restrict__ bg, float* __restrict__ bc)
{
    const int lane = threadIdx.x & 63;
    const bool biasBlk = (blockIdx.x == gridDim.x - 1);
    if (biasBlk && threadIdx.x >= 64) return;
    const float* vrow = biasBlk ? b_in
                                : W_in + (long)(blockIdx.x * 4 + (threadIdx.x >> 6)) * HD;

    float s[10] = {};
    for (int k = lane; k < HD; k += 64) {
        float a = vrow[k];
        const float4* g = (const float4*)(W_gate + (long)k * 8);
        float4 g0 = g[0], g1 = g[1];
        s[0] += a * g0.x; s[1] += a * g0.y; s[2] += a * g0.z; s[3] += a * g0.w;
        s[4] += a * g1.x; s[5] += a * g1.y; s[6] += a * g1.z; s[7] += a * g1.w;
        float2 cv = *(const float2*)(W_coef + (long)k * 2);
        s[8] += a * cv.x; s[9] += a * cv.y;
    }
    #pragma unroll
    for (int off = 32; off > 0; off >>= 1)
        #pragma unroll
        for (int e = 0; e < 10; ++e) s[e] += __shfl_xor(s[e], off);
    if (lane == 0) {
        if (biasBlk) {
            #pragma unroll
            for (int e = 0; e < 8; ++e) bg[e] = s[e];
            bc[0] = s[8] + b_coef[0];
            bc[1] = s[9] + b_coef[1];
        } else {
            const int r = blockIdx.x * 4 + (threadIdx.x >> 6);
            #pragma unroll
            for (int e = 0; e < 8; ++e) wgp[(long)r * 8 + e] = s[e];
            wcp[(long)r * 2 + 0] = s[8];
            wcp[(long)r * 2 + 1] = s[9];
        }
    }
}

// ---------------------------------------------------------------------------
// Gating from x with fused weights (one wave per token) + fused x->bf16 cast.
// ---------------------------------------------------------------------------
__global__ __launch_bounds__(256)
void gating_k(const float* __restrict__ x,
              const float* __restrict__ Wg,   // [H,8] fused
              const float* __restrict__ Wc,   // [H,2] fused
              const float* __restrict__ bg,   // [8]
              const float* __restrict__ bc,   // [2]
              unsigned short* __restrict__ xb,
              int* __restrict__ eidx,
              float* __restrict__ gval,
              float* __restrict__ coef0,
              float* __restrict__ coef1)
{
    const int tok = (blockIdx.x * 256 + threadIdx.x) >> 6;
    const int lane = threadIdx.x & 63;
    const float* row = x + (long)tok * HD;
    unsigned short* orow = xb + (long)tok * HD;

    float acc[8] = {};
    float c0 = 0.f, c1 = 0.f;
    for (int i = 0; i < HD / 64; ++i) {
        int k = i * 64 + lane;
        float tv = row[k];
        orow[k] = f2bf(tv);                      // fused x -> bf16 (coalesced)
        const float4* wg = (const float4*)(Wg + (long)k * 8);
        float4 w0 = wg[0], w1 = wg[1];
        acc[0] = fmaf(tv, w0.x, acc[0]); acc[1] = fmaf(tv, w0.y, acc[1]);
        acc[2] = fmaf(tv, w0.z, acc[2]); acc[3] = fmaf(tv, w0.w, acc[3]);
        acc[4] = fmaf(tv, w1.x, acc[4]); acc[5] = fmaf(tv, w1.y, acc[5]);
        acc[6] = fmaf(tv, w1.z, acc[6]); acc[7] = fmaf(tv, w1.w, acc[7]);
        float2 wcv = *(const float2*)(Wc + (long)k * 2);
        c0 = fmaf(tv, wcv.x, c0);
        c1 = fmaf(tv, wcv.y, c1);
    }
    #pragma unroll
    for (int off = 32; off > 0; off >>= 1) {
        #pragma unroll
        for (int e = 0; e < 8; ++e) acc[e] += __shfl_xor(acc[e], off);
        c0 += __shfl_xor(c0, off);
        c1 += __shfl_xor(c1, off);
    }
    if (lane == 0) {
        #pragma unroll
        for (int e = 0; e < 8; ++e) acc[e] += bg[e];
        float m = acc[0]; int best = 0;
        #pragma unroll
        for (int e = 1; e < 8; ++e) if (acc[e] > m) { m = acc[e]; best = e; }
        float s = 0.f;
        #pragma unroll
        for (int e = 0; e < 8; ++e) s += expf(acc[e] - m);
        eidx[tok] = best;
        gval[tok] = 1.0f / s;
        float l0 = c0 + bc[0], l1 = c1 + bc[1];
        float mm = fmaxf(l0, l1);
        float e0 = expf(l0 - mm), e1 = expf(l1 - mm);
        float inv = 1.0f / (e0 + e1);
        coef0[tok] = e0 * inv;
        coef1[tok] = e1 * inv;
    }
}

// ---------------------------------------------------------------------------
// Parallel capacity scan, 3 phases (integer-exact, verified round 5).
// ---------------------------------------------------------------------------
__global__ void scan_hist_k(const int* __restrict__ eidx,
                            int* __restrict__ counts,
                            int* __restrict__ idxTab)
{
    const int b = blockIdx.x;          // chunk id, 0..255
    const int lane = threadIdx.x;      // 64
    for (int j = b * 64 + lane; j < NE * CAP; j += NCHUNK * 64)
        idxTab[j] = -1;
    int e = eidx[b * 64 + lane];
    #pragma unroll
    for (int ex = 0; ex < NE; ++ex) {
        unsigned long long msk = __ballot(e == ex);
        if (lane == ex) counts[b * NE + ex] = (int)__popcll(msk);
    }
}

__global__ void scan_offsets_k(const int* __restrict__ counts,
                               int* __restrict__ offsets)
{
    const int e = threadIdx.x;         // 64 threads, 8 active
    if (e < NE) {
        int run = 0;
        for (int b = 0; b < NCHUNK; ++b) {
            offsets[b * NE + e] = run;
            run += counts[b * NE + e];
        }
    }
}

__global__ void scan_fill_k(const int* __restrict__ eidx,
                            const float* __restrict__ gval,
                            const float* __restrict__ coef0,
                            const int* __restrict__ offsets,
                            int* __restrict__ idxTab,
                            float* __restrict__ smoe)
{
    const int b = blockIdx.x;
    const int lane = threadIdx.x;
    const int tok = b * 64 + lane;
    int e = eidx[tok];
    unsigned long long below = (lane == 0) ? 0ull : ((~0ull) >> (64 - lane));
    int myrank = 0;
    #pragma unroll
    for (int ex = 0; ex < NE; ++ex) {
        unsigned long long msk = __ballot(e == ex);
        if (e == ex) myrank = (int)__popcll(msk & below) + offsets[b * NE + ex];
    }
    if (myrank < CAP) {
        idxTab[e * CAP + myrank] = tok;
        smoe[tok] = gval[tok] * coef0[tok];
    } else {
        smoe[tok] = 0.0f;
    }
}

// ---------------------------------------------------------------------------
// Workspace plan (lifetime-aliased; ~142 MB, under proven 144.4):
//   [0,40Mi):   pre-fusion W1T(16,z8)+Wr1T(2)+Winp(2) — dead after fusion;
//               h(40) overlays from FC1 on
//   [40,58Mi):  WF1T(16)+WFr1T(2)  (fused input weights; C-batch z=9)
//   [58,78Mi):  W2T(16)+Wr2T(2)+WoutT(2)  (tail weights)
//   [78,110Mi): res1 (32);  [110,142Mi): mixb (32, written j, RMW k, read m)
//   [142Mi..):  small (biases, routing arrays)
//   xb: d_out[0,32Mi) bf16 (gating..res1);  out: d_out f32 (written m)
// ---------------------------------------------------------------------------
extern "C" void kernel_launch(void* const* d_in, const int* in_sizes, int n_in,
                              void* d_out, int out_size, void* d_ws, size_t ws_size,
                              hipStream_t stream)
{
    const float* x      = (const float*)d_in[0];
    const float* W_in   = (const float*)d_in[1];
    const float* b_in   = (const float*)d_in[2];
    const float* W_gate = (const float*)d_in[3];
    const float* W1     = (const float*)d_in[4];
    const float* b1     = (const float*)d_in[5];
    const float* W2     = (const float*)d_in[6];
    const float* b2     = (const float*)d_in[7];
    const float* Wr1    = (const float*)d_in[8];
    const float* br1    = (const float*)d_in[9];
    const float* Wr2    = (const float*)d_in[10];
    const float* br2    = (const float*)d_in[11];
    const float* W_coef = (const float*)d_in[12];
    const float* b_coef = (const float*)d_in[13];
    const float* W_out  = (const float*)d_in[14];
    const float* b_out  = (const float*)d_in[15];
    float* out = (float*)d_out;

    const size_t MiB = 1024 * 1024;
    char* ws = (char*)d_ws;
    // pre-fusion (dead after fusion GEMM); h overlays [0,40Mi)
    unsigned short* W1T   = (unsigned short*)(ws + 0);         // 16 MiB (z=8)
    unsigned short* Wr1T  = (unsigned short*)(ws + 16 * MiB);  // 2 MiB (A-batch z=8)
    unsigned short* Winp  = (unsigned short*)(ws + 18 * MiB);  // 2 MiB plain cast
    unsigned short* h     = (unsigned short*)(ws + 0);         // 40 MiB overlay
    // fused input-side weights
    unsigned short* WF1T  = (unsigned short*)(ws + 40 * MiB);  // 16 MiB
    unsigned short* WFr1T = (unsigned short*)(ws + 56 * MiB);  // 2 MiB (C-batch z=8)
    // tail weights
    unsigned short* W2T   = (unsigned short*)(ws + 58 * MiB);  // 16 MiB
    unsigned short* Wr2T  = (unsigned short*)(ws + 74 * MiB);  // 2 MiB
    unsigned short* WoutT = (unsigned short*)(ws + 76 * MiB);  // 2 MiB
    unsigned short* res1  = (unsigned short*)(ws + 78 * MiB);  // 32 MiB
    unsigned short* mixb  = (unsigned short*)(ws + 110 * MiB); // 32 MiB
    char* sm = ws + 142 * MiB;
    float* wgp  = (float*)(sm);            sm += HD * 8 * 4;
    float* wcp  = (float*)(sm);            sm += HD * 2 * 4;
    float* bg   = (float*)(sm);            sm += 64;
    float* bc   = (float*)(sm);            sm += 64;
    float* bf1  = (float*)(sm);            sm += NE * HD * 4;   // b_in@W1[e]+b1[e]
    float* bfr1 = (float*)(sm);            sm += HD * 4;        // b_in@Wr1+br1
    int*   eidx = (int*)(sm);              sm += T_TOK * 4;
    float* gval = (float*)(sm);            sm += T_TOK * 4;
    float* cf0  = (float*)(sm);            sm += T_TOK * 4;
    float* cf1  = (float*)(sm);            sm += T_TOK * 4;
    float* smoe = (float*)(sm);            sm += T_TOK * 4;
    int* idxTab = (int*)(sm);              sm += NE * CAP * 4;
    int* counts = (int*)(sm);              sm += NCHUNK * NE * 4;
    int* offs   = (int*)(sm);              sm += NCHUNK * NE * 4;
    unsigned short* xb = (unsigned short*)d_out;   // bf16, dead after res1
    (void)ws_size; (void)in_sizes; (void)n_in; (void)out_size;

    const long HD2 = (long)HD * HD;
    dim3 blk(256);
    dim3 blkG(512);
    dim3 gBig(HD / 128, T_TOK / 256, 1);   // 8 x 64 = 512 blocks (%8==0)
    dim3 gExp(HD / 128, CAP / 256, NE);    // 8 x 10 x 8 = 640 blocks (%8==0)
    dim3 gFuse(HD / 128, HD / 256, 9);     // 8 x 4 x 9 = 288 blocks (%8==0)
    dim3 gPrep(16, 16, 20);                // all weight transposes + Winp cast

    // 1. combined weight prep (one launch: 5 transposes + plain cast)
    prep_weights_k<<<gPrep, blk, 0, stream>>>(W1, W2, Wr1, Wr2, W_out, W_in,
                                              W1T, W2T, Wr1T, Wr2T, WoutT, Winp);
    // 2. fused gating weights + gate biases (one launch; bias in last block)
    wsmall_k<<<HD / 4 + 1, blk, 0, stream>>>(W_in, b_in, W_gate, W_coef, b_coef,
                                             wgp, wcp, bg, bc);
    // 3. fused biases bf1, bfr1 (R13/R14/R17-verified)
    vecmat_init_k<<<dim3(HD/256, NE), blk, 0, stream>>>(b1, HD, bf1, HD);
    vecmat_acc_k <<<dim3(HD/256, 8, NE), blk, 0, stream>>>(b_in, 0, W1, HD2, bf1, HD);
    vecmat_init_k<<<dim3(HD/256, 1), blk, 0, stream>>>(br1, 0, bfr1, 0);
    vecmat_acc_k <<<dim3(HD/256, 8, 1), blk, 0, stream>>>(b_in, 0, Wr1, 0, bfr1, 0);
    // 4. gating from x (f32 routing) + fused x->bf16 cast into d_out
    gating_k<<<T_TOK / 4, blk, 0, stream>>>(x, wgp, wcp, bg, bc, xb,
                                            eidx, gval, cf0, cf1);
    // 5. parallel capacity scan
    scan_hist_k<<<NCHUNK, 64, 0, stream>>>(eidx, counts, idxTab);
    scan_offsets_k<<<1, 64, 0, stream>>>(counts, offs);
    scan_fill_k<<<NCHUNK, 64, 0, stream>>>(eidx, gval, cf0, offs, idxTab, smoe);
    // 6. input-side weight fusion: [WF1T(8), WFr1T] = [W1T(8), Wr1T] x Winp
    //    (z=9 batched; orientation refcheck-verified in R13/R14/R17)
    gemm_bf16_k<false, false, false, false, true><<<gFuse, blkG, 0, stream>>>(
        W1T, Winp, nullptr, WF1T, HD, HD, HD, nullptr, nullptr,
        HD2, 0, 0, 0, HD2);
    // 7. FC1: h[e] = relu(gather(xb) @ WF1[e] + bf1[e])  bf16, empty-tile exit
    gemm_bf16_k<true, true, false, false, true><<<gExp, blkG, 0, stream>>>(
        xb, WF1T, bf1, h, CAP, HD, HD, idxTab, nullptr,
        0, HD2, HD, CAP, (long)CAP * HD);
    // 8. res1 = relu(xb @ WFr1 + bfr1)   bf16
    gemm_bf16_k<false, true, false, false, true><<<gBig, blkG, 0, stream>>>(
        xb, WFr1T, bfr1, res1, T_TOK, HD, HD, nullptr, nullptr,
        0, 0, 0, 0, 0);
    // 9. j: mixb = bf16((res1 @ Wr2 + br2) * cf1[row])  bf16 (halved WRITE)
    gemm_bf16_k<false, false, true, false, true><<<gBig, blkG, 0, stream>>>(
        res1, Wr2T, br2, mixb, T_TOK, HD, HD, nullptr, cf1,
        0, 0, 0, 0, 0);
    // 10. k: mixb[tok] = bf16(f32(mixb[tok]) + (h[e]@W2[e]+b2[e])*smoe[tok])
    //     in-place bf16 RMW, empty-tile exit; dropped rows already final
    gemm_bf16_k<false, false, false, true, true><<<gExp, blkG, 0, stream>>>(
        h, W2T, b2, mixb, CAP, HD, HD, idxTab, smoe,
        (long)CAP * HD, HD2, HD, CAP, 0);
    // 11. m: out = mixb @ W_out + b_out   f32 -> d_out
    gemm_bf16_k<false, false, false, false, false><<<gBig, blkG, 0, stream>>>(
        mixb, WoutT, b_out, out, T_TOK, HD, HD, nullptr, nullptr,
        0, 0, 0, 0, 0);
}